// Round 6
// baseline (950.086 us; speedup 1.0000x reference)
//
#include <hip/hip_runtime.h>
#include <hip/hip_bf16.h>

typedef __bf16 v8bf __attribute__((ext_vector_type(8)));
typedef __bf16 v4bf __attribute__((ext_vector_type(4)));
typedef float  v4f  __attribute__((ext_vector_type(4)));

constexpr int N_NODES = 50000;
constexpr int N_EDGES = 800000;
constexpr float LN_EPS = 1e-6f;
constexpr int ROW_TILES = N_NODES / 16;   // 3125, exact

// ---------------- int-width probe (robust to int32/int64 device ints) ----------------
__global__ void probe_kernel(const int* __restrict__ edge, int* __restrict__ flag) {
  int t = threadIdx.x;           // 64 lanes
  int nz = 0;
  for (int i = t * 2 + 1; i < 4096; i += 128) nz |= (edge[i] != 0);
  unsigned long long m = __ballot(nz);
  if (t == 0) flag[0] = (m == 0ull) ? 1 : 0;
}

__device__ __forceinline__ int ld_idx(const void* base, int i, int is64) {
  int v;
  if (is64) v = (int)((const long long*)base)[(long long)i];
  else      v = ((const int*)base)[i];
  if ((unsigned)v >= (unsigned)N_NODES) v = 0;   // defensive clamp
  return v;
}

// ---------------- graph preprocessing ----------------

__global__ void init_deg_kernel(int* __restrict__ deg) {
  int i = blockIdx.x * 256 + threadIdx.x;
  if (i < N_NODES) deg[i] = 1;              // self-loop
}

__global__ void count_kernel(const void* __restrict__ edge, const int* __restrict__ flag,
                             int* __restrict__ deg) {
  int e = blockIdx.x * 256 + threadIdx.x;
  if (e < N_EDGES) atomicAdd(&deg[ld_idx(edge, N_EDGES + e, flag[0])], 1);
}

__global__ __launch_bounds__(1024) void scan_kernel(
    const int* __restrict__ deg, int* __restrict__ rowptr,
    int* __restrict__ cursor, float* __restrict__ dinv) {
  __shared__ int ps[1024];
  int t = threadIdx.x;
  constexpr int CH = (N_NODES + 1023) / 1024;   // 49
  int i0 = t * CH;
  int i1 = min(N_NODES, i0 + CH);
  int s = 0;
  for (int i = i0; i < i1; i++) s += deg[i] - 1;  // real in-edges only
  ps[t] = s;
  __syncthreads();
  for (int off = 1; off < 1024; off <<= 1) {
    int v = (t >= off) ? ps[t - off] : 0;
    __syncthreads();
    ps[t] += v;
    __syncthreads();
  }
  int run = ps[t] - s;   // exclusive base
  for (int i = i0; i < i1; i++) {
    rowptr[i] = run;
    cursor[i] = run;
    int d = max(deg[i], 1);
    run += d - 1;
    dinv[i] = rsqrtf((float)d);
  }
  if (t == 0) rowptr[N_NODES] = N_EDGES;
}

__global__ void scatter_kernel(const void* __restrict__ edge, const int* __restrict__ flag,
                               int* __restrict__ cursor, int* __restrict__ csr_src) {
  int e = blockIdx.x * 256 + threadIdx.x;
  if (e >= N_EDGES) return;
  int f = flag[0];
  int s = ld_idx(edge, e, f);
  int d = ld_idx(edge, N_EDGES + e, f);
  int pos = atomicAdd(&cursor[d], 1);
  if ((unsigned)pos < (unsigned)N_EDGES) csr_src[pos] = s;
}

// ---------------- weight packing (fp32 -> bf16 MFMA B-fragment layout) ----------------
// Wp[((kc*16 + ct)*64 + lane)*8 + j] = W[kc*32 + (lane>>4)*8 + j][ct*16 + (lane&15)]
__global__ void pack_w_kernel(const float* __restrict__ W, __bf16* __restrict__ Wp) {
  int tid = blockIdx.x * 256 + threadIdx.x;
  int j    = tid & 7;
  int lane = (tid >> 3) & 63;
  int ct   = (tid >> 9) & 15;
  int kc   = tid >> 13;
  int k    = kc * 32 + ((lane >> 4) << 3) + j;
  int col  = ct * 16 + (lane & 15);
  Wp[tid] = (__bf16)W[k * 256 + col];
}

// ---------------- MFMA GEMM: Y[N,256] = A[N,K] @ W[K,256], A fp32, Y bf16 ----------------
template <int K>
__global__ __launch_bounds__(256, 2) void gemm_kernel(
    const float* __restrict__ A, const __bf16* __restrict__ Wp,
    __bf16* __restrict__ Y) {
  constexpr int KC = K / 32;
  int lane = threadIdx.x & 63;
  int wave = threadIdx.x >> 6;

  v8bf bfrag[KC][4];
#pragma unroll
  for (int kc = 0; kc < KC; kc++)
#pragma unroll
    for (int c4 = 0; c4 < 4; c4++) {
      int ct = wave * 4 + c4;
      bfrag[kc][c4] = *(const v8bf*)(Wp + ((kc * 16 + ct) * 64 + lane) * 8);
    }

  int arow = lane & 15;
  int akq  = (lane >> 4) * 8;

  for (int t = blockIdx.x; t < ROW_TILES; t += gridDim.x) {
    int row0 = t * 16;
    const float* Ap = A + (size_t)(row0 + arow) * K + akq;
    v8bf af[KC];
#pragma unroll
    for (int kc = 0; kc < KC; kc++) {
      v4f f0 = *(const v4f*)(Ap + kc * 32);
      v4f f1 = *(const v4f*)(Ap + kc * 32 + 4);
#pragma unroll
      for (int j = 0; j < 4; j++) { af[kc][j] = (__bf16)f0[j]; af[kc][4 + j] = (__bf16)f1[j]; }
    }

    v4f acc[4];
#pragma unroll
    for (int c4 = 0; c4 < 4; c4++) acc[c4] = (v4f){0.f, 0.f, 0.f, 0.f};

#pragma unroll
    for (int kc = 0; kc < KC; kc++)
#pragma unroll
      for (int c4 = 0; c4 < 4; c4++)
        acc[c4] = __builtin_amdgcn_mfma_f32_16x16x32_bf16(af[kc], bfrag[kc][c4], acc[c4], 0, 0, 0);

    // C/D layout: col = lane&15, row = (lane>>4)*4 + reg  [verified m89]
    int crow = row0 + ((lane >> 4) << 2);
    int ccol = wave * 64 + (lane & 15);
#pragma unroll
    for (int c4 = 0; c4 < 4; c4++)
#pragma unroll
      for (int r = 0; r < 4; r++)
        Y[(size_t)(crow + r) * 256 + ccol + c4 * 16] = (__bf16)acc[c4][r];
  }
}

// ---------------- aggregation ----------------
// z = dinv[i] * sum_e dinv[src_e]*Y[src_e] + dinv[i]^2 * Y[i] + b ; h = relu(z)+z

__device__ __forceinline__ void agg_accumulate(
    const __bf16* __restrict__ Y, const int* __restrict__ rowptr,
    const int* __restrict__ csr_src, const float* __restrict__ dinv,
    const float* __restrict__ bias, int node, int d0, float h[4]) {
  int e   = rowptr[node];
  int end = rowptr[node + 1];
  e   = max(0, min(e, N_EDGES));
  end = max(e, min(end, N_EDGES));

  float a0 = 0.f, a1 = 0.f, a2 = 0.f, a3 = 0.f;
  for (; e + 1 < end; e += 2) {
    int s0 = csr_src[e], s1 = csr_src[e + 1];
    if ((unsigned)s0 >= (unsigned)N_NODES) s0 = 0;
    if ((unsigned)s1 >= (unsigned)N_NODES) s1 = 0;
    float w0 = dinv[s0], w1 = dinv[s1];
    v4bf y0 = *(const v4bf*)(Y + (size_t)s0 * 256 + d0);
    v4bf y1 = *(const v4bf*)(Y + (size_t)s1 * 256 + d0);
    a0 += w0 * (float)y0[0] + w1 * (float)y1[0];
    a1 += w0 * (float)y0[1] + w1 * (float)y1[1];
    a2 += w0 * (float)y0[2] + w1 * (float)y1[2];
    a3 += w0 * (float)y0[3] + w1 * (float)y1[3];
  }
  if (e < end) {
    int s0 = csr_src[e];
    if ((unsigned)s0 >= (unsigned)N_NODES) s0 = 0;
    float w0 = dinv[s0];
    v4bf y0 = *(const v4bf*)(Y + (size_t)s0 * 256 + d0);
    a0 += w0 * (float)y0[0];
    a1 += w0 * (float)y0[1];
    a2 += w0 * (float)y0[2];
    a3 += w0 * (float)y0[3];
  }

  float di = dinv[node];
  float wself = di * di;
  v4bf ys = *(const v4bf*)(Y + (size_t)node * 256 + d0);
  v4f  bb = *(const v4f*)(bias + d0);
  float z0 = di * a0 + wself * (float)ys[0] + bb[0];
  float z1 = di * a1 + wself * (float)ys[1] + bb[1];
  float z2 = di * a2 + wself * (float)ys[2] + bb[2];
  float z3 = di * a3 + wself * (float)ys[3] + bb[3];
  h[0] = z0 + fmaxf(z0, 0.f);
  h[1] = z1 + fmaxf(z1, 0.f);
  h[2] = z2 + fmaxf(z2, 0.f);
  h[3] = z3 + fmaxf(z3, 0.f);
}

// H intermediate stored as FLOAT32 (in the channel's own out region)
__global__ __launch_bounds__(256) void agg_mid_kernel(
    const __bf16* __restrict__ Y, const int* __restrict__ rowptr,
    const int* __restrict__ csr_src, const float* __restrict__ dinv,
    const float* __restrict__ bias, float* __restrict__ H) {
  int node = blockIdx.x * 4 + (threadIdx.x >> 6);
  int lane = threadIdx.x & 63;
  int d0 = lane * 4;
  float h[4];
  agg_accumulate(Y, rowptr, csr_src, dinv, bias, node, d0, h);
  *(v4f*)(H + (size_t)node * 256 + d0) = (v4f){h[0], h[1], h[2], h[3]};
}

__global__ __launch_bounds__(256) void agg_final_kernel(
    const __bf16* __restrict__ Y, const int* __restrict__ rowptr,
    const int* __restrict__ csr_src, const float* __restrict__ dinv,
    const float* __restrict__ bias, const float* __restrict__ lnw,
    const float* __restrict__ lnb, float* __restrict__ out) {
  int node = blockIdx.x * 4 + (threadIdx.x >> 6);
  int lane = threadIdx.x & 63;
  int d0 = lane * 4;
  float h[4];
  agg_accumulate(Y, rowptr, csr_src, dinv, bias, node, d0, h);

  float s1 = h[0] + h[1] + h[2] + h[3];
  float s2 = h[0]*h[0] + h[1]*h[1] + h[2]*h[2] + h[3]*h[3];
#pragma unroll
  for (int off = 32; off > 0; off >>= 1) {
    s1 += __shfl_xor(s1, off);
    s2 += __shfl_xor(s2, off);
  }
  float mean = s1 * (1.0f / 256.0f);
  float var  = s2 * (1.0f / 256.0f) - mean * mean;
  float rstd = rsqrtf(fmaxf(var, 0.f) + LN_EPS);

  v4f wv = *(const v4f*)(lnw + d0);
  v4f bv = *(const v4f*)(lnb + d0);
  v4f o;
#pragma unroll
  for (int j = 0; j < 4; j++)
    o[j] = (h[j] - mean) * rstd * wv[j] + bv[j];
  *(v4f*)(out + (size_t)node * 256 + d0) = o;
}

__global__ void batchs_kernel(const void* __restrict__ batch, const int* __restrict__ flag,
                              float* __restrict__ ob) {
  int i = blockIdx.x * 256 + threadIdx.x;
  if (i >= N_NODES) return;
  int f = flag[0];
  int v;
  if (f) v = (int)((const long long*)batch)[i];
  else   v = ((const int*)batch)[i];
  float b = (float)v;
  ob[i] = b;
  ob[N_NODES + i] = b;
}

// ---------------- launch ----------------

extern "C" void kernel_launch(void* const* d_in, const int* in_sizes, int n_in,
                              void* d_out, int out_size, void* d_ws, size_t ws_size,
                              hipStream_t stream) {
  const float* x    = (const float*)d_in[0];
  const void*  edge = d_in[1];
  const void*  batch= d_in[2];
  const float* W0   = (const float*)d_in[3];
  const float* b0   = (const float*)d_in[4];
  const float* W1   = (const float*)d_in[5];
  const float* b1   = (const float*)d_in[6];
  const float* W2   = (const float*)d_in[7];
  const float* b2   = (const float*)d_in[8];
  const float* lnw  = (const float*)d_in[9];
  const float* lnb  = (const float*)d_in[10];

  // Output is FLOAT32 (evidence: R3-R5 errors = bf16-pair-viewed-as-f32 of my
  // batchs writes, e.g. 0x427C427C = 63.07 -> err 65.2). Layout per docs:
  // chunk0 = out [2,50000,256] f32, chunk1 = batchs [2,50000] f32.
  float* out_x = (float*)d_out;
  float* out_b = (float*)d_out + (size_t)2 * N_NODES * 256;

  // workspace layout — ~29.8 MB (same proven footprint)
  char* p = (char*)d_ws;
  __bf16* Ybuf = (__bf16*)p;  p += (size_t)N_NODES * 256 * 2;      // 25,600,000
  int* csr_src = (int*)p;     p += (size_t)N_EDGES * 4;            //  3,200,000
  int* deg     = (int*)p;     p += (size_t)N_NODES * 4;
  int* cursor  = (int*)p;     p += (size_t)N_NODES * 4;
  int* rowptr  = (int*)p;     p += (size_t)(N_NODES + 1) * 4 + 12;
  float* dinv  = (float*)p;   p += (size_t)N_NODES * 4;
  int* flag    = (int*)p;     p += 16;
  __bf16* Wp   = (__bf16*)p;                                       //    655,360 bytes

  const int EB = (N_EDGES + 255) / 256;   // 3125
  const int NB = (N_NODES + 255) / 256;   // 196

  probe_kernel<<<1, 64, 0, stream>>>((const int*)edge, flag);
  init_deg_kernel<<<NB, 256, 0, stream>>>(deg);
  count_kernel<<<EB, 256, 0, stream>>>(edge, flag, deg);
  scan_kernel<<<1, 1024, 0, stream>>>(deg, rowptr, cursor, dinv);
  scatter_kernel<<<EB, 256, 0, stream>>>(edge, flag, cursor, csr_src);

  for (int c = 0; c < 2; c++) {
    pack_w_kernel<<<128, 256, 0, stream>>>(W0 + (size_t)c * 128 * 256, Wp + c * 32768);
    pack_w_kernel<<<256, 256, 0, stream>>>(W1 + (size_t)c * 256 * 256, Wp + 65536 + c * 65536);
    pack_w_kernel<<<256, 256, 0, stream>>>(W2 + (size_t)c * 256 * 256, Wp + 196608 + c * 65536);
  }

  for (int c = 0; c < 2; c++) {
    // H intermediate (f32) lives in the channel's own final-output region;
    // agg_final overwrites it last. No aliasing across kernel boundaries.
    float* Hc = out_x + (size_t)c * N_NODES * 256;
    gemm_kernel<128><<<625, 256, 0, stream>>>(x, Wp + c * 32768, Ybuf);
    agg_mid_kernel<<<N_NODES / 4, 256, 0, stream>>>(Ybuf, rowptr, csr_src, dinv, b0 + c * 256, Hc);
    gemm_kernel<256><<<625, 256, 0, stream>>>(Hc, Wp + 65536 + c * 65536, Ybuf);
    agg_mid_kernel<<<N_NODES / 4, 256, 0, stream>>>(Ybuf, rowptr, csr_src, dinv, b1 + c * 256, Hc);
    gemm_kernel<256><<<625, 256, 0, stream>>>(Hc, Wp + 196608 + c * 65536, Ybuf);
    agg_final_kernel<<<N_NODES / 4, 256, 0, stream>>>(Ybuf, rowptr, csr_src, dinv, b2 + c * 256,
                                                      lnw, lnb, Hc);
  }

  batchs_kernel<<<NB, 256, 0, stream>>>(batch, flag, out_b);
}

// Round 7
// 795.434 us; speedup vs baseline: 1.1944x; 1.1944x over previous
//
#include <hip/hip_runtime.h>
#include <hip/hip_bf16.h>

typedef __bf16 v8bf __attribute__((ext_vector_type(8)));
typedef __bf16 v4bf __attribute__((ext_vector_type(4)));
typedef float  v4f  __attribute__((ext_vector_type(4)));

constexpr int N_NODES = 50000;
constexpr int N_EDGES = 800000;
constexpr float LN_EPS = 1e-6f;
constexpr int ROW_TILES = N_NODES / 16;   // 3125, exact

// ---------------- int-width probe (robust to int32/int64 device ints) ----------------
__global__ void probe_kernel(const int* __restrict__ edge, int* __restrict__ flag) {
  int t = threadIdx.x;           // 64 lanes
  int nz = 0;
  for (int i = t * 2 + 1; i < 4096; i += 128) nz |= (edge[i] != 0);
  unsigned long long m = __ballot(nz);
  if (t == 0) flag[0] = (m == 0ull) ? 1 : 0;
}

__device__ __forceinline__ int ld_idx(const void* base, int i, int is64) {
  int v;
  if (is64) v = (int)((const long long*)base)[(long long)i];
  else      v = ((const int*)base)[i];
  if ((unsigned)v >= (unsigned)N_NODES) v = 0;   // defensive clamp
  return v;
}

// ---------------- graph preprocessing ----------------

__global__ void init_kernel(int* __restrict__ deg, int* __restrict__ gcount) {
  int i = blockIdx.x * 256 + threadIdx.x;
  if (i < N_NODES) deg[i] = 1;              // self-loop
  if (i == 0) gcount[0] = 0;
}

__global__ void count_kernel(const void* __restrict__ edge, const int* __restrict__ flag,
                             int* __restrict__ deg) {
  int e = blockIdx.x * 256 + threadIdx.x;
  if (e < N_EDGES) atomicAdd(&deg[ld_idx(edge, N_EDGES + e, flag[0])], 1);
}

// Per-block LDS scan + atomic block-base. CSR ranges need only be disjoint,
// not monotone in node id, since agg derives [start, start+deg-1) per node.
__global__ __launch_bounds__(256) void block_offsets_kernel(
    const int* __restrict__ deg, int* __restrict__ gcount,
    int* __restrict__ rowstart, int* __restrict__ cursor, float* __restrict__ dinv) {
  __shared__ int ps[256];
  __shared__ int base_s;
  int tid = threadIdx.x;
  int node = blockIdx.x * 256 + tid;
  int d = (node < N_NODES) ? deg[node] : 1;
  int cnt = d - 1;                           // real in-edges for this node
  ps[tid] = cnt;
  __syncthreads();
#pragma unroll
  for (int off = 1; off < 256; off <<= 1) {
    int v = (tid >= off) ? ps[tid - off] : 0;
    __syncthreads();
    ps[tid] += v;
    __syncthreads();
  }
  if (tid == 255) base_s = atomicAdd(gcount, ps[255]);
  __syncthreads();
  int start = base_s + ps[tid] - cnt;        // exclusive within block + block base
  if (node < N_NODES) {
    rowstart[node] = start;
    cursor[node]   = start;
    dinv[node]     = rsqrtf((float)max(d, 1));
  }
}

__global__ void scatter_kernel(const void* __restrict__ edge, const int* __restrict__ flag,
                               int* __restrict__ cursor, int* __restrict__ csr_src) {
  int e = blockIdx.x * 256 + threadIdx.x;
  if (e >= N_EDGES) return;
  int f = flag[0];
  int s = ld_idx(edge, e, f);
  int d = ld_idx(edge, N_EDGES + e, f);
  int pos = atomicAdd(&cursor[d], 1);
  if ((unsigned)pos < (unsigned)N_EDGES) csr_src[pos] = s;
}

// ---------------- weight packing (fp32 -> bf16 MFMA B-fragment layout) ----------------
// Wp[((kc*16 + ct)*64 + lane)*8 + j] = W[kc*32 + (lane>>4)*8 + j][ct*16 + (lane&15)]
__global__ void pack_w_kernel(const float* __restrict__ W, __bf16* __restrict__ Wp) {
  int tid = blockIdx.x * 256 + threadIdx.x;
  int j    = tid & 7;
  int lane = (tid >> 3) & 63;
  int ct   = (tid >> 9) & 15;
  int kc   = tid >> 13;
  int k    = kc * 32 + ((lane >> 4) << 3) + j;
  int col  = ct * 16 + (lane & 15);
  Wp[tid] = (__bf16)W[k * 256 + col];
}

// ---------------- MFMA GEMM: Y[N,256] = A[N,K] @ W[K,256], A fp32, Y bf16 ----------------
template <int K>
__global__ __launch_bounds__(256, 2) void gemm_kernel(
    const float* __restrict__ A, const __bf16* __restrict__ Wp,
    __bf16* __restrict__ Y) {
  constexpr int KC = K / 32;
  int lane = threadIdx.x & 63;
  int wave = threadIdx.x >> 6;

  v8bf bfrag[KC][4];
#pragma unroll
  for (int kc = 0; kc < KC; kc++)
#pragma unroll
    for (int c4 = 0; c4 < 4; c4++) {
      int ct = wave * 4 + c4;
      bfrag[kc][c4] = *(const v8bf*)(Wp + ((kc * 16 + ct) * 64 + lane) * 8);
    }

  int arow = lane & 15;
  int akq  = (lane >> 4) * 8;

  for (int t = blockIdx.x; t < ROW_TILES; t += gridDim.x) {
    int row0 = t * 16;
    const float* Ap = A + (size_t)(row0 + arow) * K + akq;
    v8bf af[KC];
#pragma unroll
    for (int kc = 0; kc < KC; kc++) {
      v4f f0 = *(const v4f*)(Ap + kc * 32);
      v4f f1 = *(const v4f*)(Ap + kc * 32 + 4);
#pragma unroll
      for (int j = 0; j < 4; j++) { af[kc][j] = (__bf16)f0[j]; af[kc][4 + j] = (__bf16)f1[j]; }
    }

    v4f acc[4];
#pragma unroll
    for (int c4 = 0; c4 < 4; c4++) acc[c4] = (v4f){0.f, 0.f, 0.f, 0.f};

#pragma unroll
    for (int kc = 0; kc < KC; kc++)
#pragma unroll
      for (int c4 = 0; c4 < 4; c4++)
        acc[c4] = __builtin_amdgcn_mfma_f32_16x16x32_bf16(af[kc], bfrag[kc][c4], acc[c4], 0, 0, 0);

    // C/D layout: col = lane&15, row = (lane>>4)*4 + reg  [verified m89]
    int crow = row0 + ((lane >> 4) << 2);
    int ccol = wave * 64 + (lane & 15);
#pragma unroll
    for (int c4 = 0; c4 < 4; c4++)
#pragma unroll
      for (int r = 0; r < 4; r++)
        Y[(size_t)(crow + r) * 256 + ccol + c4 * 16] = (__bf16)acc[c4][r];
  }
}

// ---------------- aggregation ----------------
// z = dinv[i] * sum_e dinv[src_e]*Y[src_e] + dinv[i]^2 * Y[i] + b ; h = relu(z)+z
// One wave per node; lane owns 4 dims; unroll-4 for outstanding gathers.

__device__ __forceinline__ void agg_accumulate(
    const __bf16* __restrict__ Y, const int* __restrict__ rowstart,
    const int* __restrict__ deg, const int* __restrict__ csr_src,
    const float* __restrict__ dinv, const float* __restrict__ bias,
    int node, int d0, float h[4]) {
  int start = rowstart[node];
  int cnt   = deg[node] - 1;
  start = max(0, min(start, N_EDGES));
  cnt   = max(0, min(cnt, N_EDGES - start));
  int e = start, end = start + cnt;

  float a0 = 0.f, a1 = 0.f, a2 = 0.f, a3 = 0.f;
  for (; e + 3 < end; e += 4) {
    int s0 = csr_src[e],     s1 = csr_src[e + 1];
    int s2 = csr_src[e + 2], s3 = csr_src[e + 3];
    if ((unsigned)s0 >= (unsigned)N_NODES) s0 = 0;
    if ((unsigned)s1 >= (unsigned)N_NODES) s1 = 0;
    if ((unsigned)s2 >= (unsigned)N_NODES) s2 = 0;
    if ((unsigned)s3 >= (unsigned)N_NODES) s3 = 0;
    float w0 = dinv[s0], w1 = dinv[s1], w2 = dinv[s2], w3 = dinv[s3];
    v4bf y0 = *(const v4bf*)(Y + (size_t)s0 * 256 + d0);
    v4bf y1 = *(const v4bf*)(Y + (size_t)s1 * 256 + d0);
    v4bf y2 = *(const v4bf*)(Y + (size_t)s2 * 256 + d0);
    v4bf y3 = *(const v4bf*)(Y + (size_t)s3 * 256 + d0);
    a0 += w0 * (float)y0[0] + w1 * (float)y1[0] + w2 * (float)y2[0] + w3 * (float)y3[0];
    a1 += w0 * (float)y0[1] + w1 * (float)y1[1] + w2 * (float)y2[1] + w3 * (float)y3[1];
    a2 += w0 * (float)y0[2] + w1 * (float)y1[2] + w2 * (float)y2[2] + w3 * (float)y3[2];
    a3 += w0 * (float)y0[3] + w1 * (float)y1[3] + w2 * (float)y2[3] + w3 * (float)y3[3];
  }
  for (; e < end; e++) {
    int s0 = csr_src[e];
    if ((unsigned)s0 >= (unsigned)N_NODES) s0 = 0;
    float w0 = dinv[s0];
    v4bf y0 = *(const v4bf*)(Y + (size_t)s0 * 256 + d0);
    a0 += w0 * (float)y0[0];
    a1 += w0 * (float)y0[1];
    a2 += w0 * (float)y0[2];
    a3 += w0 * (float)y0[3];
  }

  float di = dinv[node];
  float wself = di * di;
  v4bf ys = *(const v4bf*)(Y + (size_t)node * 256 + d0);
  v4f  bb = *(const v4f*)(bias + d0);
  float z0 = di * a0 + wself * (float)ys[0] + bb[0];
  float z1 = di * a1 + wself * (float)ys[1] + bb[1];
  float z2 = di * a2 + wself * (float)ys[2] + bb[2];
  float z3 = di * a3 + wself * (float)ys[3] + bb[3];
  h[0] = z0 + fmaxf(z0, 0.f);
  h[1] = z1 + fmaxf(z1, 0.f);
  h[2] = z2 + fmaxf(z2, 0.f);
  h[3] = z3 + fmaxf(z3, 0.f);
}

// H intermediate stored as FLOAT32 (in the channel's own out region)
__global__ __launch_bounds__(256) void agg_mid_kernel(
    const __bf16* __restrict__ Y, const int* __restrict__ rowstart,
    const int* __restrict__ deg, const int* __restrict__ csr_src,
    const float* __restrict__ dinv, const float* __restrict__ bias,
    float* __restrict__ H) {
  int node = blockIdx.x * 4 + (threadIdx.x >> 6);
  int lane = threadIdx.x & 63;
  int d0 = lane * 4;
  float h[4];
  agg_accumulate(Y, rowstart, deg, csr_src, dinv, bias, node, d0, h);
  *(v4f*)(H + (size_t)node * 256 + d0) = (v4f){h[0], h[1], h[2], h[3]};
}

__global__ __launch_bounds__(256) void agg_final_kernel(
    const __bf16* __restrict__ Y, const int* __restrict__ rowstart,
    const int* __restrict__ deg, const int* __restrict__ csr_src,
    const float* __restrict__ dinv, const float* __restrict__ bias,
    const float* __restrict__ lnw, const float* __restrict__ lnb,
    float* __restrict__ out) {
  int node = blockIdx.x * 4 + (threadIdx.x >> 6);
  int lane = threadIdx.x & 63;
  int d0 = lane * 4;
  float h[4];
  agg_accumulate(Y, rowstart, deg, csr_src, dinv, bias, node, d0, h);

  float s1 = h[0] + h[1] + h[2] + h[3];
  float s2 = h[0]*h[0] + h[1]*h[1] + h[2]*h[2] + h[3]*h[3];
#pragma unroll
  for (int off = 32; off > 0; off >>= 1) {
    s1 += __shfl_xor(s1, off);
    s2 += __shfl_xor(s2, off);
  }
  float mean = s1 * (1.0f / 256.0f);
  float var  = s2 * (1.0f / 256.0f) - mean * mean;
  float rstd = rsqrtf(fmaxf(var, 0.f) + LN_EPS);

  v4f wv = *(const v4f*)(lnw + d0);
  v4f bv = *(const v4f*)(lnb + d0);
  v4f o;
#pragma unroll
  for (int j = 0; j < 4; j++)
    o[j] = (h[j] - mean) * rstd * wv[j] + bv[j];
  *(v4f*)(out + (size_t)node * 256 + d0) = o;
}

__global__ void batchs_kernel(const void* __restrict__ batch, const int* __restrict__ flag,
                              float* __restrict__ ob) {
  int i = blockIdx.x * 256 + threadIdx.x;
  if (i >= N_NODES) return;
  int f = flag[0];
  int v;
  if (f) v = (int)((const long long*)batch)[i];
  else   v = ((const int*)batch)[i];
  float b = (float)v;
  ob[i] = b;
  ob[N_NODES + i] = b;
}

// ---------------- launch ----------------

extern "C" void kernel_launch(void* const* d_in, const int* in_sizes, int n_in,
                              void* d_out, int out_size, void* d_ws, size_t ws_size,
                              hipStream_t stream) {
  const float* x    = (const float*)d_in[0];
  const void*  edge = d_in[1];
  const void*  batch= d_in[2];
  const float* W0   = (const float*)d_in[3];
  const float* b0   = (const float*)d_in[4];
  const float* W1   = (const float*)d_in[5];
  const float* b1   = (const float*)d_in[6];
  const float* W2   = (const float*)d_in[7];
  const float* b2   = (const float*)d_in[8];
  const float* lnw  = (const float*)d_in[9];
  const float* lnb  = (const float*)d_in[10];

  // Output layout (verified R6): chunk0 = out [2,50000,256] f32, chunk1 = batchs f32.
  float* out_x = (float*)d_out;
  float* out_b = (float*)d_out + (size_t)2 * N_NODES * 256;

  // workspace layout — ~29.8 MB
  char* p = (char*)d_ws;
  __bf16* Ybuf  = (__bf16*)p;  p += (size_t)N_NODES * 256 * 2;     // 25,600,000
  int* csr_src  = (int*)p;     p += (size_t)N_EDGES * 4;           //  3,200,000
  int* deg      = (int*)p;     p += (size_t)N_NODES * 4;
  int* cursor   = (int*)p;     p += (size_t)N_NODES * 4;
  int* rowstart = (int*)p;     p += (size_t)N_NODES * 4;
  float* dinv   = (float*)p;   p += (size_t)N_NODES * 4;
  int* flag     = (int*)p;     p += 16;
  int* gcount   = (int*)p;     p += 16;
  __bf16* Wp    = (__bf16*)p;                                      //    655,360 bytes

  const int EB = (N_EDGES + 255) / 256;   // 3125
  const int NB = (N_NODES + 255) / 256;   // 196

  probe_kernel<<<1, 64, 0, stream>>>((const int*)edge, flag);
  init_kernel<<<NB, 256, 0, stream>>>(deg, gcount);
  count_kernel<<<EB, 256, 0, stream>>>(edge, flag, deg);
  block_offsets_kernel<<<NB, 256, 0, stream>>>(deg, gcount, rowstart, cursor, dinv);
  scatter_kernel<<<EB, 256, 0, stream>>>(edge, flag, cursor, csr_src);

  for (int c = 0; c < 2; c++) {
    pack_w_kernel<<<128, 256, 0, stream>>>(W0 + (size_t)c * 128 * 256, Wp + c * 32768);
    pack_w_kernel<<<256, 256, 0, stream>>>(W1 + (size_t)c * 256 * 256, Wp + 65536 + c * 65536);
    pack_w_kernel<<<256, 256, 0, stream>>>(W2 + (size_t)c * 256 * 256, Wp + 196608 + c * 65536);
  }

  for (int c = 0; c < 2; c++) {
    // H intermediate (f32) lives in the channel's own final-output region;
    // agg_final overwrites it last.
    float* Hc = out_x + (size_t)c * N_NODES * 256;
    gemm_kernel<128><<<625, 256, 0, stream>>>(x, Wp + c * 32768, Ybuf);
    agg_mid_kernel<<<N_NODES / 4, 256, 0, stream>>>(Ybuf, rowstart, deg, csr_src, dinv,
                                                    b0 + c * 256, Hc);
    gemm_kernel<256><<<625, 256, 0, stream>>>(Hc, Wp + 65536 + c * 65536, Ybuf);
    agg_mid_kernel<<<N_NODES / 4, 256, 0, stream>>>(Ybuf, rowstart, deg, csr_src, dinv,
                                                    b1 + c * 256, Hc);
    gemm_kernel<256><<<625, 256, 0, stream>>>(Hc, Wp + 196608 + c * 65536, Ybuf);
    agg_final_kernel<<<N_NODES / 4, 256, 0, stream>>>(Ybuf, rowstart, deg, csr_src, dinv,
                                                      b2 + c * 256, lnw, lnb, Hc);
  }

  batchs_kernel<<<NB, 256, 0, stream>>>(batch, flag, out_b);
}